// Round 7
// baseline (3032.698 us; speedup 1.0000x reference)
//
#include <hip/hip_runtime.h>
#include <hip/hip_bf16.h>

// LSTM T=4096, B=16, I=64, H=256 (4H=1024 gate rows), O=1.
//
// R22 = R21 + raw-barrier step sync (lgkmcnt-only drain).
// R21 verified 2748-2757us kernel (total 2933), absmax 0.001953125.
// Step = 1611 cyc = ~1015 MFMA-busy (63%) + ~595 handoff. Theory: the
// per-step __syncthreads() lowers to s_waitcnt vmcnt(0) lgkmcnt(0) +
// s_barrier (m97-documented), and the vmcnt(0) drain exposes the tail of
// the per-step xg HBM/L3 prefetch (~600-900 cyc latency vs ~600-800 cyc
// of cover) at EVERY barrier. The xg load is per-lane private (consumed
// by the same lane next step) — only the h ds_write needs cross-wave
// visibility, which lgkmcnt(0) alone provides. Replace with:
//   asm("s_waitcnt lgkmcnt(0)" ::: "memory");  // h write retired
//   __builtin_amdgcn_s_barrier();              // raw barrier, no vm drain
//   asm("" ::: "memory");                      // no ds_read hoist above
// (pattern verified in the 8-phase GEMM template, m201).
// All arithmetic byte-identical to R21 => absmax 0.001953125 expected.
//
// Step decomposition and rejected levers (R12/R14/R16/R18/R20): see R21.
//
// Structure (verified R10/R11/R13/R19/R21): 16 WGs x 1024 thr (16 waves,
// 4/SIMD). Wave w, lane col=l&15 owns unit u=w*16+col; gate rows g*256+u.
// Per-gate-row symmetric int8 quant, preact = (rowmax/127^2 * log2e-scale)
// *acc_int + xg(pre-scaled), int32 exact. h int8 in LDS identity layout
// (4x b128 broadcast, 0 conflicts), double-buffered; magic-number RNE
// h-quantize; ONE barrier/step; all-lane redundant epilogue; xg fp16
// prefetched via pointer.

typedef _Float16 f16x2 __attribute__((ext_vector_type(2)));
typedef _Float16 f16x4 __attribute__((ext_vector_type(4)));
typedef int      i32x4 __attribute__((ext_vector_type(4)));

#define T_STEPS 4096
#define BATCH   16
#define IN      64
#define HID     256
#define G4      1024

#define LOG2E 1.44269504088896f

__device__ __forceinline__ float fdot2(f16x2 a, f16x2 b, float c) {
#if __has_builtin(__builtin_amdgcn_fdot2)
    return __builtin_amdgcn_fdot2(a, b, c, false);
#else
    return c + (float)a.x * (float)b.x + (float)a.y * (float)b.y;
#endif
}

__device__ __forceinline__ float fast_rcp(float x) {
#if __has_builtin(__builtin_amdgcn_rcpf)
    return __builtin_amdgcn_rcpf(x);
#else
    return 1.0f / x;
#endif
}

__device__ __forceinline__ float exp2_fast(float x) {
#if __has_builtin(__builtin_amdgcn_exp2f)
    return __builtin_amdgcn_exp2f(x);
#else
    return exp2f(x);
#endif
}

// sig2(x2) = sigmoid(x) where x2 = x*log2e  (one exp2, neg via modifier)
__device__ __forceinline__ float sig2(float x2) {
    return fast_rcp(1.0f + exp2_fast(-x2));
}
// th2(x2) = tanh(x) where x2 = x*2*log2e
__device__ __forceinline__ float th2(float x2) {
    return __builtin_fmaf(2.0f, fast_rcp(1.0f + exp2_fast(-x2)), -1.0f);
}

// unscaled helpers (fallback kernel only)
__device__ __forceinline__ float sigf(float x) {
    return fast_rcp(1.0f + __expf(-x));
}
__device__ __forceinline__ float tanh_fast(float x) {
    return 2.0f * sigf(2.0f * x) - 1.0f;
}

// ---------------- Kernel A: x_gates precompute (transposed, log2e-scaled) --
__global__ __launch_bounds__(256) void xg_precompute(
    const float* __restrict__ x, const float* __restrict__ W_ih,
    const float* __restrict__ b_ih, const float* __restrict__ b_hh,
    _Float16* __restrict__ xg)
{
    const int b   = blockIdx.x;
    const int t0  = blockIdx.y * 128;
    const int tid = threadIdx.x;

    __shared__ __align__(16) f16x2 xs2[IN / 2];

    f16x2 wih[4][32];
    float bias[4];
    const float2* W2 = (const float2*)W_ih;
    #pragma unroll
    for (int g = 0; g < 4; ++g) {
        const int r = tid + g * 256;
        #pragma unroll
        for (int m = 0; m < 32; ++m) {
            float2 v = W2[r * 32 + m];
            wih[g][m] = f16x2{(_Float16)v.x, (_Float16)v.y};
        }
        bias[g] = b_ih[r] + b_hh[r];
    }

    // per-gate epilogue pre-scale: sig gates * log2e, tanh gate * 2log2e
    const float esc[4] = {LOG2E, LOG2E, 2.0f * LOG2E, LOG2E};

    for (int tt = 0; tt < 128; ++tt) {
        const int t = t0 + tt;
        if (tid < 32) {
            float2 v = ((const float2*)x)[(t * BATCH + b) * 32 + tid];
            xs2[tid] = f16x2{(_Float16)v.x, (_Float16)v.y};
        }
        __syncthreads();
        float acc[4] = {bias[0], bias[1], bias[2], bias[3]};
        #pragma unroll
        for (int m = 0; m < 32; ++m) {
            f16x2 xv = xs2[m];
            #pragma unroll
            for (int g = 0; g < 4; ++g) acc[g] = fdot2(wih[g][m], xv, acc[g]);
        }
        f16x4 v4 = f16x4{(_Float16)(acc[0] * esc[0]), (_Float16)(acc[1] * esc[1]),
                         (_Float16)(acc[2] * esc[2]), (_Float16)(acc[3] * esc[3])};
        ((f16x4*)xg)[(t * BATCH + b) * 256 + tid] = v4;
        __syncthreads();
    }
}

// ---------------- Kernel B: i8-MFMA persistent recurrence ----------------
__global__ __launch_bounds__(1024, 4) void lstm_mfma(
    const float* __restrict__ W_hh,  const float* __restrict__ W_lin,
    const float* __restrict__ b_lin, const float* __restrict__ h0,
    const float* __restrict__ c0,    const _Float16* __restrict__ xg,
    float* __restrict__ out)
{
    const int b   = blockIdx.x;
    const int tid = threadIdx.x;
    const int w   = tid >> 6;     // wave 0..15
    const int l   = tid & 63;     // lane
    const int col = l & 15;       // MFMA col for this lane
    const int g4  = l >> 4;       // k lane-group 0..3

    __shared__ __align__(16) signed char hs[2][256];  // h int8, identity layout
    __shared__ float esh[256];

    const int u = w * 16 + col;   // unit this lane covers

    // ---- one-time: per-gate-row max, then W_hh -> int8 B-fragments ----
    const float4* Wh4 = (const float4*)W_hh;          // row stride 64 float4
    float qs[4], ksc[4];
    {
        float rm[4];
        #pragma unroll
        for (int g = 0; g < 4; ++g) {
            const int row = g * 256 + u;
            float m = 0.0f;
            #pragma unroll
            for (int c = 0; c < 4; ++c) {
                #pragma unroll
                for (int d = 0; d < 4; ++d) {
                    float4 v = Wh4[row * 64 + 16 * c + 4 * g4 + d];
                    m = fmaxf(m, fmaxf(fmaxf(fabsf(v.x), fabsf(v.y)),
                                       fmaxf(fabsf(v.z), fabsf(v.w))));
                }
            }
            rm[g] = m;
        }
        const float esc[4] = {LOG2E, LOG2E, 2.0f * LOG2E, LOG2E};
        #pragma unroll
        for (int g = 0; g < 4; ++g) {                  // max across g4 groups
            rm[g] = fmaxf(rm[g], __shfl_xor(rm[g], 16, 64));
            rm[g] = fmaxf(rm[g], __shfl_xor(rm[g], 32, 64));
            rm[g] = fmaxf(rm[g], 1e-20f);
            qs[g]  = 127.0f / rm[g];
            ksc[g] = rm[g] * (1.0f / 16129.0f) * esc[g];   // rm/127^2 * exp2 scale
        }
    }
    i32x4 wf[4][4];
    #pragma unroll
    for (int g = 0; g < 4; ++g) {
        const int row = g * 256 + u;
        #pragma unroll
        for (int c = 0; c < 4; ++c) {
            union { int i[4]; i32x4 v; } uu;
            #pragma unroll
            for (int d = 0; d < 4; ++d) {
                float4 v = Wh4[row * 64 + 16 * c + 4 * g4 + d];
                int b0 = (int)rintf(v.x * qs[g]) & 255;
                int b1 = (int)rintf(v.y * qs[g]) & 255;
                int b2 = (int)rintf(v.z * qs[g]) & 255;
                int b3 = (int)rintf(v.w * qs[g]) & 255;
                uu.i[d] = b0 | (b1 << 8) | (b2 << 16) | (b3 << 24);
            }
            wf[g][c] = uu.v;
        }
    }

    // ---- state (lane l<16 owns unit u's write) ----
    const float MAGIC = 12582912.0f;                   // 1.5 * 2^23
    const float TWO_LOG2E = 2.0f * LOG2E;
    float cs2  = c0[b * HID + u] * TWO_LOG2E;          // 2log2e-scaled c-state
    float hval = h0[b * HID + u];
    if (l < 16) {
        union { float f; int i; } m0;
        m0.f = __builtin_fmaf(hval, 127.0f, MAGIC);    // RNE int in low bits
        hs[0][u] = (signed char)(m0.i & 0xff);
    }

    union XU { uint2 i; f16x4 h; };
    const uint2* xp = (const uint2*)xg + b * 256 + u;  // stride BATCH*256/step
    XU xc; xc.i = *xp;
    xp += BATCH * 256;

    for (int t = 0; t < T_STEPS; ++t) {
        // h(t) in hs[t&1] visible: lgkmcnt-only drain + raw barrier.
        // (__syncthreads would also drain vmcnt(0), exposing the xg
        // prefetch's HBM/L3 latency at every step.)
        asm volatile("s_waitcnt lgkmcnt(0)" ::: "memory");
        __builtin_amdgcn_s_barrier();
        asm volatile("" ::: "memory");   // no ds_read hoist above barrier

        // A fragments: chunk c = bytes [64c + 16*g4, +16) -> 4x b128 broadcast
        const uint4* hsv = (const uint4*)(&hs[t & 1][0]);
        union AU { uint4 q; i32x4 v; } a0, a1, a2, a3;
        a0.q = hsv[g4];
        a1.q = hsv[4 + g4];
        a2.q = hsv[8 + g4];
        a3.q = hsv[12 + g4];

        // prefetch next step's x-gates (pointer-incremented)
        XU xn;
        if (t + 1 < T_STEPS) { xn.i = *xp; xp += BATCH * 256; }
        else                 { xn = xc; }

        i32x4 acc0 = {0, 0, 0, 0};
        i32x4 acc1 = {0, 0, 0, 0};
        i32x4 acc2 = {0, 0, 0, 0};
        i32x4 acc3 = {0, 0, 0, 0};

        // a-major order (verified R13/R19): first 4 MFMAs need only a0 ->
        // compute starts at lgkmcnt(3), remaining ds_read latency hidden.
        acc0 = __builtin_amdgcn_mfma_i32_16x16x64_i8(a0.v, wf[0][0], acc0, 0, 0, 0);
        acc1 = __builtin_amdgcn_mfma_i32_16x16x64_i8(a0.v, wf[1][0], acc1, 0, 0, 0);
        acc2 = __builtin_amdgcn_mfma_i32_16x16x64_i8(a0.v, wf[2][0], acc2, 0, 0, 0);
        acc3 = __builtin_amdgcn_mfma_i32_16x16x64_i8(a0.v, wf[3][0], acc3, 0, 0, 0);
        acc0 = __builtin_amdgcn_mfma_i32_16x16x64_i8(a1.v, wf[0][1], acc0, 0, 0, 0);
        acc1 = __builtin_amdgcn_mfma_i32_16x16x64_i8(a1.v, wf[1][1], acc1, 0, 0, 0);
        acc2 = __builtin_amdgcn_mfma_i32_16x16x64_i8(a1.v, wf[2][1], acc2, 0, 0, 0);
        acc3 = __builtin_amdgcn_mfma_i32_16x16x64_i8(a1.v, wf[3][1], acc3, 0, 0, 0);
        acc0 = __builtin_amdgcn_mfma_i32_16x16x64_i8(a2.v, wf[0][2], acc0, 0, 0, 0);
        acc1 = __builtin_amdgcn_mfma_i32_16x16x64_i8(a2.v, wf[1][2], acc1, 0, 0, 0);
        acc2 = __builtin_amdgcn_mfma_i32_16x16x64_i8(a2.v, wf[2][2], acc2, 0, 0, 0);
        acc3 = __builtin_amdgcn_mfma_i32_16x16x64_i8(a2.v, wf[3][2], acc3, 0, 0, 0);
        acc0 = __builtin_amdgcn_mfma_i32_16x16x64_i8(a3.v, wf[0][3], acc0, 0, 0, 0);
        acc1 = __builtin_amdgcn_mfma_i32_16x16x64_i8(a3.v, wf[1][3], acc1, 0, 0, 0);
        acc2 = __builtin_amdgcn_mfma_i32_16x16x64_i8(a3.v, wf[2][3], acc2, 0, 0, 0);
        acc3 = __builtin_amdgcn_mfma_i32_16x16x64_i8(a3.v, wf[3][3], acc3, 0, 0, 0);

        // D rows identical -> acc reg0 of ANY lane = int preact(col).
        // All-lane redundant epilogue; preacts already exp2-scaled.
        float p0 = __builtin_fmaf((float)acc0[0], ksc[0], (float)xc.h[0]);
        float p1 = __builtin_fmaf((float)acc1[0], ksc[1], (float)xc.h[1]);
        float p2 = __builtin_fmaf((float)acc2[0], ksc[2], (float)xc.h[2]);
        float p3 = __builtin_fmaf((float)acc3[0], ksc[3], (float)xc.h[3]);
        float gi = sig2(p0);
        float gf = sig2(p1);
        float gg = th2(p2);
        float go = sig2(p3);
        float gig = gi * gg * TWO_LOG2E;               // off the gf-wait chain
        cs2 = __builtin_fmaf(gf, cs2, gig);            // c-state (2log2e-scaled)
        float thc    = th2(cs2);                       // tanh(c)
        float thc127 = thc * 127.0f;
        if (l < 16) {
            union { float f; int i; } mg;
            mg.f = __builtin_fmaf(go, thc127, MAGIC);  // RNE, low byte = i8
            hs[(t + 1) & 1][u] = (signed char)(mg.i & 0xff);
        }
        if (t == T_STEPS - 1) hval = go * thc;         // full-precision h_T
        xc = xn;
    }

    // ---- epilogue: y[b] = sigmoid(h . W_lin + b_lin) ----
    if (l < 16) esh[u] = hval * W_lin[u];
    __syncthreads();
    if (tid == 0) {
        float z = b_lin[0];
        for (int n = 0; n < 256; ++n) z += esh[n];
        out[b] = sigf(z);
    }
}

// ---------------- Fallback (ws too small): R6 dot2 kernel, x streamed ------
#define NTHR 768
#define KC   11
#define REGC 8
#define LDSC 3
#define HPAD 264
#define WT_OFF   0
#define HB_OFF   147456
#define PS_OFF   148512
#define ESH_OFF  156704
#define SMEM_BYTES 157728
typedef _Float16 f16x8 __attribute__((ext_vector_type(8)));

__global__ __launch_bounds__(NTHR, 3) void lstm_fb(
    const float* __restrict__ x,     const float* __restrict__ W_ih,
    const float* __restrict__ W_hh,  const float* __restrict__ b_ih,
    const float* __restrict__ b_hh,  const float* __restrict__ W_lin,
    const float* __restrict__ b_lin, const float* __restrict__ h0,
    const float* __restrict__ c0,    float* __restrict__ out)
{
    const int b   = blockIdx.x;
    const int tid = threadIdx.x;
    const int j   = tid & 255;
    const int s   = tid >> 8;

    extern __shared__ __align__(16) char smem[];
    f16x8*    wt8  = (f16x8*)(smem + WT_OFF);
    _Float16* hbuf = (_Float16*)(smem + HB_OFF);
    float4*   psum = (float4*)(smem + PS_OFF);
    float*    esh  = (float*)(smem + ESH_OFF);

    f16x2 wr[128];
    const float4* Wh4 = (const float4*)W_hh;
    #pragma unroll
    for (int g = 0; g < 4; ++g) {
        const int r = j + 256 * g;
        #pragma unroll
        for (int c = 0; c < REGC; ++c) {
            const int f4i = r * 64 + (88 * s + 8 * c) / 4;
            float4 a = Wh4[f4i];
            float4 d = Wh4[f4i + 1];
            wr[g * 32 + c * 4 + 0] = f16x2{(_Float16)a.x, (_Float16)a.y};
            wr[g * 32 + c * 4 + 1] = f16x2{(_Float16)a.z, (_Float16)a.w};
            wr[g * 32 + c * 4 + 2] = f16x2{(_Float16)d.x, (_Float16)d.y};
            wr[g * 32 + c * 4 + 3] = f16x2{(_Float16)d.z, (_Float16)d.w};
        }
        #pragma unroll
        for (int c = 0; c < LDSC; ++c) {
            const int k0 = 88 * s + 8 * (REGC + c);
            union { f16x8 v; f16x2 p[4]; } u;
            if (k0 < 256) {
                float4 a = Wh4[r * 64 + k0 / 4];
                float4 d = Wh4[r * 64 + k0 / 4 + 1];
                u.p[0] = f16x2{(_Float16)a.x, (_Float16)a.y};
                u.p[1] = f16x2{(_Float16)a.z, (_Float16)a.w};
                u.p[2] = f16x2{(_Float16)d.x, (_Float16)d.y};
                u.p[3] = f16x2{(_Float16)d.z, (_Float16)d.w};
            } else {
                u.p[0] = f16x2{0, 0}; u.p[1] = f16x2{0, 0};
                u.p[2] = f16x2{0, 0}; u.p[3] = f16x2{0, 0};
            }
            wt8[(g * LDSC + c) * NTHR + tid] = u.v;
        }
    }

    float bias[4] = {0.f, 0.f, 0.f, 0.f};
    if (s == 0) {
        #pragma unroll
        for (int g = 0; g < 4; ++g)
            bias[g] = b_ih[j + g * 256] + b_hh[j + g * 256];
    }

    float cst = 0.f, hval = 0.f;
    if (s == 0) {
        cst  = c0[b * HID + j];
        hval = h0[b * HID + j];
        hbuf[j] = (_Float16)hval;
    }
    if (tid < 8) {
        hbuf[256 + tid]        = (_Float16)0.f;
        hbuf[HPAD + 256 + tid] = (_Float16)0.f;
    }

    for (int t = 0; t < T_STEPS; ++t) {
        __syncthreads();
        const f16x8* hb = (const f16x8*)(hbuf + (t & 1) * HPAD);

        float acc[4] = {0.f, 0.f, 0.f, 0.f};
        if (s != 0) {
            const float4* Wi4 = (const float4*)W_ih;
            const float4* xv4 = (const float4*)(x + ((size_t)t * BATCH + b) * IN)
                                + (s - 1) * 8;
            #pragma unroll
            for (int q = 0; q < 8; ++q) {
                float4 xv = xv4[q];
                #pragma unroll
                for (int g = 0; g < 4; ++g) {
                    float4 wv = Wi4[(j + 256 * g) * 16 + (s - 1) * 8 + q];
                    acc[g] += wv.x * xv.x + wv.y * xv.y + wv.z * xv.z + wv.w * xv.w;
                }
            }
        }
        #pragma unroll
        for (int c = 0; c < REGC; ++c) {
            union { f16x8 v; f16x2 p[4]; } hu;
            hu.v = hb[s * KC + c];
            #pragma unroll
            for (int uu = 0; uu < 4; ++uu) {
                #pragma unroll
                for (int g = 0; g < 4; ++g)
                    acc[g] = fdot2(wr[g * 32 + c * 4 + uu], hu.p[uu], acc[g]);
            }
        }
        #pragma unroll
        for (int c = 0; c < LDSC; ++c) {
            union { f16x8 v; f16x2 p[4]; } hu;
            hu.v = hb[s * KC + REGC + c];
            #pragma unroll
            for (int g = 0; g < 4; ++g) {
                union { f16x8 v; f16x2 p[4]; } wu;
                wu.v = wt8[(g * LDSC + c) * NTHR + tid];
                #pragma unroll
                for (int uu = 0; uu < 4; ++uu)
                    acc[g] = fdot2(wu.p[uu], hu.p[uu], acc[g]);
            }
        }
        if (s != 0)
            psum[(s - 1) * 256 + j] = float4{acc[0], acc[1], acc[2], acc[3]};
        __syncthreads();
        if (s == 0) {
            float4 p1 = psum[j];
            float4 p2 = psum[256 + j];
            float gi = sigf(acc[0] + p1.x + p2.x + bias[0]);
            float gf = sigf(acc[1] + p1.y + p2.y + bias[1]);
            float gg = tanh_fast(acc[2] + p1.z + p2.z + bias[2]);
            float go = sigf(acc[3] + p1.w + p2.w + bias[3]);
            cst  = gf * cst + gi * gg;
            hval = go * tanh_fast(cst);
            hbuf[((t + 1) & 1) * HPAD + j] = (_Float16)hval;
        }
    }

    if (s == 0) esh[j] = hval * W_lin[j];
    __syncthreads();
    if (tid == 0) {
        float z = b_lin[0];
        for (int n = 0; n < 256; ++n) z += esh[n];
        out[b] = sigf(z);
    }
}

extern "C" void kernel_launch(void* const* d_in, const int* in_sizes, int n_in,
                              void* d_out, int out_size, void* d_ws, size_t ws_size,
                              hipStream_t stream) {
    const float* x     = (const float*)d_in[0];
    const float* W_ih  = (const float*)d_in[1];
    const float* W_hh  = (const float*)d_in[2];
    const float* b_ih  = (const float*)d_in[3];
    const float* b_hh  = (const float*)d_in[4];
    const float* W_lin = (const float*)d_in[5];
    const float* b_lin = (const float*)d_in[6];
    const float* h0    = (const float*)d_in[7];
    const float* c0    = (const float*)d_in[8];
    float* out = (float*)d_out;

    const size_t need = (size_t)T_STEPS * BATCH * G4 * sizeof(_Float16); // 128 MB
    if (ws_size >= need) {
        _Float16* xg = (_Float16*)d_ws;
        xg_precompute<<<dim3(BATCH, 32), 256, 0, stream>>>(x, W_ih, b_ih, b_hh, xg);
        lstm_mfma<<<dim3(BATCH), 1024, 0, stream>>>(
            W_hh, W_lin, b_lin, h0, c0, xg, out);
    } else {
        (void)hipFuncSetAttribute((const void*)lstm_fb,
                                  hipFuncAttributeMaxDynamicSharedMemorySize,
                                  SMEM_BYTES);
        lstm_fb<<<dim3(BATCH), NTHR, SMEM_BYTES, stream>>>(
            x, W_ih, W_hh, b_ih, b_hh, W_lin, b_lin, h0, c0, out);
    }
}

// Round 9
// 2932.270 us; speedup vs baseline: 1.0342x; 1.0342x over previous
//
#include <hip/hip_runtime.h>
#include <hip/hip_bf16.h>

// LSTM T=4096, B=16, I=64, H=256 (4H=1024 gate rows), O=1.
//
// R24 = R23 RETRY (round-8 bench was an infra failure: "container failed
// twice", no diagnostics; kernel is byte-identical to the R21 lstm_mfma
// verified in round 6 at 2748-2757us, total 2933, absmax 0.001953125).
//
// R22 post-mortem: raw lgkmcnt-only barrier REGRESSED (+85us). The xg
// prefetch is consumed one full step after issue (~1600 cyc cover > ~900
// cyc latency) so __syncthreads' vmcnt(0) drain was free; the asm "memory"
// clobbers only removed scheduler freedom. Keep plain __syncthreads.
//
// Measured-rejected handoff levers: distributed epilogue (R12), indep
// accumulators (R14), VALU dot-split (R16/R18: no v_dot on gfx950),
// chain-major issue (R20), raw barrier (R22). Arithmetic-rejected:
// cross-CU spread (per-step device-scope exchange ~900-1400 cyc > ~700 cyc
// issue saved), MX-fp8 K=128 (-15% issue, 8x h-quant error).
// Step = 1611 cyc = ~1015 MFMA-pipe busy (63%) + ~595 serial handoff
// (ds_read ~120 + activation chain ~150 + write/barrier skew/drain).
//
// Structure (verified R10/R11/R13/R19/R21): 16 WGs x 1024 thr (16 waves,
// 4/SIMD). Wave w, lane col=l&15 owns unit u=w*16+col; gate rows g*256+u.
// Per-gate-row symmetric int8 quant, preact = (rowmax/127^2 * log2e-scale)
// *acc_int + xg(pre-scaled), int32 exact. h int8 in LDS identity layout
// (4x b128 broadcast, 0 conflicts), double-buffered; magic-number RNE
// h-quantize; ONE barrier/step; all-lane redundant epilogue; xg fp16
// prefetched via pointer. Epilogue trims (R19/R21): xg pre-scaled by
// log2e (2log2e tanh gate), ksc scale-folded, cs2=2log2e*c tracked,
// thc127 precomputed, per-step hval multiply deleted.

typedef _Float16 f16x2 __attribute__((ext_vector_type(2)));
typedef _Float16 f16x4 __attribute__((ext_vector_type(4)));
typedef int      i32x4 __attribute__((ext_vector_type(4)));

#define T_STEPS 4096
#define BATCH   16
#define IN      64
#define HID     256
#define G4      1024

#define LOG2E 1.44269504088896f

__device__ __forceinline__ float fdot2(f16x2 a, f16x2 b, float c) {
#if __has_builtin(__builtin_amdgcn_fdot2)
    return __builtin_amdgcn_fdot2(a, b, c, false);
#else
    return c + (float)a.x * (float)b.x + (float)a.y * (float)b.y;
#endif
}

__device__ __forceinline__ float fast_rcp(float x) {
#if __has_builtin(__builtin_amdgcn_rcpf)
    return __builtin_amdgcn_rcpf(x);
#else
    return 1.0f / x;
#endif
}

__device__ __forceinline__ float exp2_fast(float x) {
#if __has_builtin(__builtin_amdgcn_exp2f)
    return __builtin_amdgcn_exp2f(x);
#else
    return exp2f(x);
#endif
}

// sig2(x2) = sigmoid(x) where x2 = x*log2e  (one exp2, neg via modifier)
__device__ __forceinline__ float sig2(float x2) {
    return fast_rcp(1.0f + exp2_fast(-x2));
}
// th2(x2) = tanh(x) where x2 = x*2*log2e
__device__ __forceinline__ float th2(float x2) {
    return __builtin_fmaf(2.0f, fast_rcp(1.0f + exp2_fast(-x2)), -1.0f);
}

// unscaled helpers (fallback kernel only)
__device__ __forceinline__ float sigf(float x) {
    return fast_rcp(1.0f + __expf(-x));
}
__device__ __forceinline__ float tanh_fast(float x) {
    return 2.0f * sigf(2.0f * x) - 1.0f;
}

// ---------------- Kernel A: x_gates precompute (transposed, log2e-scaled) --
__global__ __launch_bounds__(256) void xg_precompute(
    const float* __restrict__ x, const float* __restrict__ W_ih,
    const float* __restrict__ b_ih, const float* __restrict__ b_hh,
    _Float16* __restrict__ xg)
{
    const int b   = blockIdx.x;
    const int t0  = blockIdx.y * 128;
    const int tid = threadIdx.x;

    __shared__ __align__(16) f16x2 xs2[IN / 2];

    f16x2 wih[4][32];
    float bias[4];
    const float2* W2 = (const float2*)W_ih;
    #pragma unroll
    for (int g = 0; g < 4; ++g) {
        const int r = tid + g * 256;
        #pragma unroll
        for (int m = 0; m < 32; ++m) {
            float2 v = W2[r * 32 + m];
            wih[g][m] = f16x2{(_Float16)v.x, (_Float16)v.y};
        }
        bias[g] = b_ih[r] + b_hh[r];
    }

    // per-gate epilogue pre-scale: sig gates * log2e, tanh gate * 2log2e
    const float esc[4] = {LOG2E, LOG2E, 2.0f * LOG2E, LOG2E};

    for (int tt = 0; tt < 128; ++tt) {
        const int t = t0 + tt;
        if (tid < 32) {
            float2 v = ((const float2*)x)[(t * BATCH + b) * 32 + tid];
            xs2[tid] = f16x2{(_Float16)v.x, (_Float16)v.y};
        }
        __syncthreads();
        float acc[4] = {bias[0], bias[1], bias[2], bias[3]};
        #pragma unroll
        for (int m = 0; m < 32; ++m) {
            f16x2 xv = xs2[m];
            #pragma unroll
            for (int g = 0; g < 4; ++g) acc[g] = fdot2(wih[g][m], xv, acc[g]);
        }
        f16x4 v4 = f16x4{(_Float16)(acc[0] * esc[0]), (_Float16)(acc[1] * esc[1]),
                         (_Float16)(acc[2] * esc[2]), (_Float16)(acc[3] * esc[3])};
        ((f16x4*)xg)[(t * BATCH + b) * 256 + tid] = v4;
        __syncthreads();
    }
}

// ---------------- Kernel B: i8-MFMA persistent recurrence ----------------
__global__ __launch_bounds__(1024, 4) void lstm_mfma(
    const float* __restrict__ W_hh,  const float* __restrict__ W_lin,
    const float* __restrict__ b_lin, const float* __restrict__ h0,
    const float* __restrict__ c0,    const _Float16* __restrict__ xg,
    float* __restrict__ out)
{
    const int b   = blockIdx.x;
    const int tid = threadIdx.x;
    const int w   = tid >> 6;     // wave 0..15
    const int l   = tid & 63;     // lane
    const int col = l & 15;       // MFMA col for this lane
    const int g4  = l >> 4;       // k lane-group 0..3

    __shared__ __align__(16) signed char hs[2][256];  // h int8, identity layout
    __shared__ float esh[256];

    const int u = w * 16 + col;   // unit this lane covers

    // ---- one-time: per-gate-row max, then W_hh -> int8 B-fragments ----
    const float4* Wh4 = (const float4*)W_hh;          // row stride 64 float4
    float qs[4], ksc[4];
    {
        float rm[4];
        #pragma unroll
        for (int g = 0; g < 4; ++g) {
            const int row = g * 256 + u;
            float m = 0.0f;
            #pragma unroll
            for (int c = 0; c < 4; ++c) {
                #pragma unroll
                for (int d = 0; d < 4; ++d) {
                    float4 v = Wh4[row * 64 + 16 * c + 4 * g4 + d];
                    m = fmaxf(m, fmaxf(fmaxf(fabsf(v.x), fabsf(v.y)),
                                       fmaxf(fabsf(v.z), fabsf(v.w))));
                }
            }
            rm[g] = m;
        }
        const float esc[4] = {LOG2E, LOG2E, 2.0f * LOG2E, LOG2E};
        #pragma unroll
        for (int g = 0; g < 4; ++g) {                  // max across g4 groups
            rm[g] = fmaxf(rm[g], __shfl_xor(rm[g], 16, 64));
            rm[g] = fmaxf(rm[g], __shfl_xor(rm[g], 32, 64));
            rm[g] = fmaxf(rm[g], 1e-20f);
            qs[g]  = 127.0f / rm[g];
            ksc[g] = rm[g] * (1.0f / 16129.0f) * esc[g];   // rm/127^2 * exp2 scale
        }
    }
    i32x4 wf[4][4];
    #pragma unroll
    for (int g = 0; g < 4; ++g) {
        const int row = g * 256 + u;
        #pragma unroll
        for (int c = 0; c < 4; ++c) {
            union { int i[4]; i32x4 v; } uu;
            #pragma unroll
            for (int d = 0; d < 4; ++d) {
                float4 v = Wh4[row * 64 + 16 * c + 4 * g4 + d];
                int b0 = (int)rintf(v.x * qs[g]) & 255;
                int b1 = (int)rintf(v.y * qs[g]) & 255;
                int b2 = (int)rintf(v.z * qs[g]) & 255;
                int b3 = (int)rintf(v.w * qs[g]) & 255;
                uu.i[d] = b0 | (b1 << 8) | (b2 << 16) | (b3 << 24);
            }
            wf[g][c] = uu.v;
        }
    }

    // ---- state (lane l<16 owns unit u's write) ----
    const float MAGIC = 12582912.0f;                   // 1.5 * 2^23
    const float TWO_LOG2E = 2.0f * LOG2E;
    float cs2  = c0[b * HID + u] * TWO_LOG2E;          // 2log2e-scaled c-state
    float hval = h0[b * HID + u];
    if (l < 16) {
        union { float f; int i; } m0;
        m0.f = __builtin_fmaf(hval, 127.0f, MAGIC);    // RNE int in low bits
        hs[0][u] = (signed char)(m0.i & 0xff);
    }

    union XU { uint2 i; f16x4 h; };
    const uint2* xp = (const uint2*)xg + b * 256 + u;  // stride BATCH*256/step
    XU xc; xc.i = *xp;
    xp += BATCH * 256;

    for (int t = 0; t < T_STEPS; ++t) {
        __syncthreads();   // h(t) in hs[t&1] visible

        // A fragments: chunk c = bytes [64c + 16*g4, +16) -> 4x b128 broadcast
        const uint4* hsv = (const uint4*)(&hs[t & 1][0]);
        union AU { uint4 q; i32x4 v; } a0, a1, a2, a3;
        a0.q = hsv[g4];
        a1.q = hsv[4 + g4];
        a2.q = hsv[8 + g4];
        a3.q = hsv[12 + g4];

        // prefetch next step's x-gates (pointer-incremented)
        XU xn;
        if (t + 1 < T_STEPS) { xn.i = *xp; xp += BATCH * 256; }
        else                 { xn = xc; }

        i32x4 acc0 = {0, 0, 0, 0};
        i32x4 acc1 = {0, 0, 0, 0};
        i32x4 acc2 = {0, 0, 0, 0};
        i32x4 acc3 = {0, 0, 0, 0};

        // a-major order (verified R13/R19): first 4 MFMAs need only a0 ->
        // compute starts at lgkmcnt(3), remaining ds_read latency hidden.
        acc0 = __builtin_amdgcn_mfma_i32_16x16x64_i8(a0.v, wf[0][0], acc0, 0, 0, 0);
        acc1 = __builtin_amdgcn_mfma_i32_16x16x64_i8(a0.v, wf[1][0], acc1, 0, 0, 0);
        acc2 = __builtin_amdgcn_mfma_i32_16x16x64_i8(a0.v, wf[2][0], acc2, 0, 0, 0);
        acc3 = __builtin_amdgcn_mfma_i32_16x16x64_i8(a0.v, wf[3][0], acc3, 0, 0, 0);
        acc0 = __builtin_amdgcn_mfma_i32_16x16x64_i8(a1.v, wf[0][1], acc0, 0, 0, 0);
        acc1 = __builtin_amdgcn_mfma_i32_16x16x64_i8(a1.v, wf[1][1], acc1, 0, 0, 0);
        acc2 = __builtin_amdgcn_mfma_i32_16x16x64_i8(a1.v, wf[2][1], acc2, 0, 0, 0);
        acc3 = __builtin_amdgcn_mfma_i32_16x16x64_i8(a1.v, wf[3][1], acc3, 0, 0, 0);
        acc0 = __builtin_amdgcn_mfma_i32_16x16x64_i8(a2.v, wf[0][2], acc0, 0, 0, 0);
        acc1 = __builtin_amdgcn_mfma_i32_16x16x64_i8(a2.v, wf[1][2], acc1, 0, 0, 0);
        acc2 = __builtin_amdgcn_mfma_i32_16x16x64_i8(a2.v, wf[2][2], acc2, 0, 0, 0);
        acc3 = __builtin_amdgcn_mfma_i32_16x16x64_i8(a2.v, wf[3][2], acc3, 0, 0, 0);
        acc0 = __builtin_amdgcn_mfma_i32_16x16x64_i8(a3.v, wf[0][3], acc0, 0, 0, 0);
        acc1 = __builtin_amdgcn_mfma_i32_16x16x64_i8(a3.v, wf[1][3], acc1, 0, 0, 0);
        acc2 = __builtin_amdgcn_mfma_i32_16x16x64_i8(a3.v, wf[2][3], acc2, 0, 0, 0);
        acc3 = __builtin_amdgcn_mfma_i32_16x16x64_i8(a3.v, wf[3][3], acc3, 0, 0, 0);

        // D rows identical -> acc reg0 of ANY lane = int preact(col).
        // All-lane redundant epilogue; preacts already exp2-scaled.
        float p0 = __builtin_fmaf((float)acc0[0], ksc[0], (float)xc.h[0]);
        float p1 = __builtin_fmaf((float)acc1[0], ksc[1], (float)xc.h[1]);
        float p2 = __builtin_fmaf((float)acc2[0], ksc[2], (float)xc.h[2]);
        float p3 = __builtin_fmaf((float)acc3[0], ksc[3], (float)xc.h[3]);
        float gi = sig2(p0);
        float gf = sig2(p1);
        float gg = th2(p2);
        float go = sig2(p3);
        float gig = gi * gg * TWO_LOG2E;               // off the gf-wait chain
        cs2 = __builtin_fmaf(gf, cs2, gig);            // c-state (2log2e-scaled)
        float thc    = th2(cs2);                       // tanh(c)
        float thc127 = thc * 127.0f;
        if (l < 16) {
            union { float f; int i; } mg;
            mg.f = __builtin_fmaf(go, thc127, MAGIC);  // RNE, low byte = i8
            hs[(t + 1) & 1][u] = (signed char)(mg.i & 0xff);
        }
        if (t == T_STEPS - 1) hval = go * thc;         // full-precision h_T
        xc = xn;
    }

    // ---- epilogue: y[b] = sigmoid(h . W_lin + b_lin) ----
    if (l < 16) esh[u] = hval * W_lin[u];
    __syncthreads();
    if (tid == 0) {
        float z = b_lin[0];
        for (int n = 0; n < 256; ++n) z += esh[n];
        out[b] = sigf(z);
    }
}

// ---------------- Fallback (ws too small): R6 dot2 kernel, x streamed ------
#define NTHR 768
#define KC   11
#define REGC 8
#define LDSC 3
#define HPAD 264
#define WT_OFF   0
#define HB_OFF   147456
#define PS_OFF   148512
#define ESH_OFF  156704
#define SMEM_BYTES 157728
typedef _Float16 f16x8 __attribute__((ext_vector_type(8)));

__global__ __launch_bounds__(NTHR, 3) void lstm_fb(
    const float* __restrict__ x,     const float* __restrict__ W_ih,
    const float* __restrict__ W_hh,  const float* __restrict__ b_ih,
    const float* __restrict__ b_hh,  const float* __restrict__ W_lin,
    const float* __restrict__ b_lin, const float* __restrict__ h0,
    const float* __restrict__ c0,    float* __restrict__ out)
{
    const int b   = blockIdx.x;
    const int tid = threadIdx.x;
    const int j   = tid & 255;
    const int s   = tid >> 8;

    extern __shared__ __align__(16) char smem[];
    f16x8*    wt8  = (f16x8*)(smem + WT_OFF);
    _Float16* hbuf = (_Float16*)(smem + HB_OFF);
    float4*   psum = (float4*)(smem + PS_OFF);
    float*    esh  = (float*)(smem + ESH_OFF);

    f16x2 wr[128];
    const float4* Wh4 = (const float4*)W_hh;
    #pragma unroll
    for (int g = 0; g < 4; ++g) {
        const int r = j + 256 * g;
        #pragma unroll
        for (int c = 0; c < REGC; ++c) {
            const int f4i = r * 64 + (88 * s + 8 * c) / 4;
            float4 a = Wh4[f4i];
            float4 d = Wh4[f4i + 1];
            wr[g * 32 + c * 4 + 0] = f16x2{(_Float16)a.x, (_Float16)a.y};
            wr[g * 32 + c * 4 + 1] = f16x2{(_Float16)a.z, (_Float16)a.w};
            wr[g * 32 + c * 4 + 2] = f16x2{(_Float16)d.x, (_Float16)d.y};
            wr[g * 32 + c * 4 + 3] = f16x2{(_Float16)d.z, (_Float16)d.w};
        }
        #pragma unroll
        for (int c = 0; c < LDSC; ++c) {
            const int k0 = 88 * s + 8 * (REGC + c);
            union { f16x8 v; f16x2 p[4]; } u;
            if (k0 < 256) {
                float4 a = Wh4[r * 64 + k0 / 4];
                float4 d = Wh4[r * 64 + k0 / 4 + 1];
                u.p[0] = f16x2{(_Float16)a.x, (_Float16)a.y};
                u.p[1] = f16x2{(_Float16)a.z, (_Float16)a.w};
                u.p[2] = f16x2{(_Float16)d.x, (_Float16)d.y};
                u.p[3] = f16x2{(_Float16)d.z, (_Float16)d.w};
            } else {
                u.p[0] = f16x2{0, 0}; u.p[1] = f16x2{0, 0};
                u.p[2] = f16x2{0, 0}; u.p[3] = f16x2{0, 0};
            }
            wt8[(g * LDSC + c) * NTHR + tid] = u.v;
        }
    }

    float bias[4] = {0.f, 0.f, 0.f, 0.f};
    if (s == 0) {
        #pragma unroll
        for (int g = 0; g < 4; ++g)
            bias[g] = b_ih[j + g * 256] + b_hh[j + g * 256];
    }

    float cst = 0.f, hval = 0.f;
    if (s == 0) {
        cst  = c0[b * HID + j];
        hval = h0[b * HID + j];
        hbuf[j] = (_Float16)hval;
    }
    if (tid < 8) {
        hbuf[256 + tid]        = (_Float16)0.f;
        hbuf[HPAD + 256 + tid] = (_Float16)0.f;
    }

    for (int t = 0; t < T_STEPS; ++t) {
        __syncthreads();
        const f16x8* hb = (const f16x8*)(hbuf + (t & 1) * HPAD);

        float acc[4] = {0.f, 0.f, 0.f, 0.f};
        if (s != 0) {
            const float4* Wi4 = (const float4*)W_ih;
            const float4* xv4 = (const float4*)(x + ((size_t)t * BATCH + b) * IN)
                                + (s - 1) * 8;
            #pragma unroll
            for (int q = 0; q < 8; ++q) {
                float4 xv = xv4[q];
                #pragma unroll
                for (int g = 0; g < 4; ++g) {
                    float4 wv = Wi4[(j + 256 * g) * 16 + (s - 1) * 8 + q];
                    acc[g] += wv.x * xv.x + wv.y * xv.y + wv.z * xv.z + wv.w * xv.w;
                }
            }
        }
        #pragma unroll
        for (int c = 0; c < REGC; ++c) {
            union { f16x8 v; f16x2 p[4]; } hu;
            hu.v = hb[s * KC + c];
            #pragma unroll
            for (int uu = 0; uu < 4; ++uu) {
                #pragma unroll
                for (int g = 0; g < 4; ++g)
                    acc[g] = fdot2(wr[g * 32 + c * 4 + uu], hu.p[uu], acc[g]);
            }
        }
        #pragma unroll
        for (int c = 0; c < LDSC; ++c) {
            union { f16x8 v; f16x2 p[4]; } hu;
            hu.v = hb[s * KC + REGC + c];
            #pragma unroll
            for (int g = 0; g < 4; ++g) {
                union { f16x8 v; f16x2 p[4]; } wu;
                wu.v = wt8[(g * LDSC + c) * NTHR + tid];
                #pragma unroll
                for (int uu = 0; uu < 4; ++uu)
                    acc[g] = fdot2(wu.p[uu], hu.p[uu], acc[g]);
            }
        }
        if (s != 0)
            psum[(s - 1) * 256 + j] = float4{acc[0], acc[1], acc[2], acc[3]};
        __syncthreads();
        if (s == 0) {
            float4 p1 = psum[j];
            float4 p2 = psum[256 + j];
            float gi = sigf(acc[0] + p1.x + p2.x + bias[0]);
            float gf = sigf(acc[1] + p1.y + p2.y + bias[1]);
            float gg = tanh_fast(acc[2] + p1.z + p2.z + bias[2]);
            float go = sigf(acc[3] + p1.w + p2.w + bias[3]);
            cst  = gf * cst + gi * gg;
            hval = go * tanh_fast(cst);
            hbuf[((t + 1) & 1) * HPAD + j] = (_Float16)hval;
        }
    }

    if (s == 0) esh[j] = hval * W_lin[j];
    __syncthreads();
    if (tid == 0) {
        float z = b_lin[0];
        for (int n = 0; n < 256; ++n) z += esh[n];
        out[b] = sigf(z);
    }
}

extern "C" void kernel_launch(void* const* d_in, const int* in_sizes, int n_in,
                              void* d_out, int out_size, void* d_ws, size_t ws_size,
                              hipStream_t stream) {
    const float* x     = (const float*)d_in[0];
    const float* W_ih  = (const float*)d_in[1];
    const float* W_hh  = (const float*)d_in[2];
    const float* b_ih  = (const float*)d_in[3];
    const float* b_hh  = (const float*)d_in[4];
    const float* W_lin = (const float*)d_in[5];
    const float* b_lin = (const float*)d_in[6];
    const float* h0    = (const float*)d_in[7];
    const float* c0    = (const float*)d_in[8];
    float* out = (float*)d_out;

    const size_t need = (size_t)T_STEPS * BATCH * G4 * sizeof(_Float16); // 128 MB
    if (ws_size >= need) {
        _Float16* xg = (_Float16*)d_ws;
        xg_precompute<<<dim3(BATCH, 32), 256, 0, stream>>>(x, W_ih, b_ih, b_hh, xg);
        lstm_mfma<<<dim3(BATCH), 1024, 0, stream>>>(
            W_hh, W_lin, b_lin, h0, c0, xg, out);
    } else {
        (void)hipFuncSetAttribute((const void*)lstm_fb,
                                  hipFuncAttributeMaxDynamicSharedMemorySize,
                                  SMEM_BYTES);
        lstm_fb<<<dim3(BATCH), NTHR, SMEM_BYTES, stream>>>(
            x, W_ih, W_hh, b_ih, b_hh, W_lin, b_lin, h0, c0, out);
    }
}